// Round 1
// baseline (839.926 us; speedup 1.0000x reference)
//
#include <hip/hip_runtime.h>

// ---------- common helpers ----------
typedef __attribute__((ext_vector_type(8))) short bf16x8;
typedef __attribute__((ext_vector_type(4))) float f32x4;

__device__ __forceinline__ short f2bf(float f){
  union { float f; unsigned u; } v; v.f = f;
  unsigned r = v.u + 0x7fffu + ((v.u >> 16) & 1u);   // RNE
  return (short)(r >> 16);
}
__device__ __forceinline__ bf16x8 pack8(float4 a, float4 b){
  bf16x8 v;
  v[0]=f2bf(a.x); v[1]=f2bf(a.y); v[2]=f2bf(a.z); v[3]=f2bf(a.w);
  v[4]=f2bf(b.x); v[5]=f2bf(b.y); v[6]=f2bf(b.z); v[7]=f2bf(b.w);
  return v;
}
__device__ __forceinline__ f32x4 mfma16(bf16x8 a, bf16x8 b, f32x4 c){
  return __builtin_amdgcn_mfma_f32_16x16x32_bf16(a, b, c, 0, 0, 0);
}
__device__ __forceinline__ float sigm(float x){
  return __builtin_amdgcn_rcpf(1.f + __expf(-x));
}
__device__ __forceinline__ float tanh_(float x){
  return 1.f - 2.f*__builtin_amdgcn_rcpf(1.f + __expf(2.f*x));
}

// ---------- 1) embedding + LSTM (final h) ----------
// grid 256 blocks x 512 threads. Block owns 32 rows, wave w owns hidden
// units [16w,16w+16) for all 4 gates. gates[32,512] = x@Wih^T + h@Whh^T + b.
// MFMA 16x16x32 bf16; A-frag: lane holds A[l&15][(l>>4)*8+j];
// B-frag: B[(l>>4)*8+j][l&15]; D: lane reg r -> D[(l>>4)*4+r][l&15].
__global__ __launch_bounds__(512) void lstm_kernel(
    const int* __restrict__ tokens, const float* __restrict__ embed,
    const float* __restrict__ Wih, const float* __restrict__ Whh,
    const float* __restrict__ bih, const float* __restrict__ bhh,
    float* __restrict__ feat)
{
  __shared__ short hbuf[32*128];           // bf16, row stride 256B, XOR-swizzled
  const int tid  = threadIdx.x;
  const int wave = tid >> 6, lane = tid & 63;
  const int l15  = lane & 15, lhi = lane >> 4;     // lhi in 0..3
  const int nbase = blockIdx.x * 32;
  const int ucol  = wave*16 + l15;                 // this lane's unit column

  // W B-frags in registers: B[k][col] = W[gate*128+ucol][k]
  bf16x8 wihf[4][4], whhf[4][4];
  for(int g=0; g<4; ++g){
    const float* wi = Wih + (size_t)(g*128 + ucol)*128;
    const float* wh = Whh + (size_t)(g*128 + ucol)*128;
    #pragma unroll
    for(int kt=0; kt<4; ++kt){
      int e0 = kt*32 + lhi*8;
      float4 a0 = *(const float4*)(wi+e0), a1 = *(const float4*)(wi+e0+4);
      float4 b0 = *(const float4*)(wh+e0), b1 = *(const float4*)(wh+e0+4);
      wihf[g][kt] = pack8(a0,a1);
      whhf[g][kt] = pack8(b0,b1);
    }
  }
  float bs[4];
  #pragma unroll
  for(int g=0; g<4; ++g) bs[g] = bih[g*128+ucol] + bhh[g*128+ucol];

  float c[2][4], hreg[2][4];
  #pragma unroll
  for(int m=0;m<2;++m) for(int r=0;r<4;++r){ c[m][r]=0.f; hreg[m][r]=0.f; }

  for(int i=tid; i<32*128; i+=512) hbuf[i]=0;
  __syncthreads();

  const int trow0 = nbase + l15;
  const int trow1 = nbase + 16 + l15;

  for(int l=0; l<32; ++l){
    f32x4 acc[2][4];
    #pragma unroll
    for(int m=0;m<2;++m) for(int g=0;g<4;++g) acc[m][g]=(f32x4){0.f,0.f,0.f,0.f};

    // x A-frags from embedding gather (f32 -> bf16)
    int tok0 = tokens[trow0*32 + l];
    int tok1 = tokens[trow1*32 + l];
    const float* e0 = embed + (size_t)tok0*128;
    const float* e1 = embed + (size_t)tok1*128;
    bf16x8 xa[2][4];
    #pragma unroll
    for(int kt=0; kt<4; ++kt){
      int k0 = kt*32 + lhi*8;
      float4 u0=*(const float4*)(e0+k0), u1=*(const float4*)(e0+k0+4);
      float4 v0=*(const float4*)(e1+k0), v1=*(const float4*)(e1+k0+4);
      xa[0][kt]=pack8(u0,u1);
      xa[1][kt]=pack8(v0,v1);
    }
    // h A-frags from LDS + MFMAs
    #pragma unroll
    for(int kt=0; kt<4; ++kt){
      int sbyte = kt*64 + lhi*16;
      int r0 = l15, r1 = 16 + l15;
      int a0 = (r0*256 + sbyte) ^ ((r0&7)<<4);
      int a1 = (r1*256 + sbyte) ^ ((r1&7)<<4);
      bf16x8 h0 = *(const bf16x8*)((const char*)hbuf + a0);
      bf16x8 h1 = *(const bf16x8*)((const char*)hbuf + a1);
      #pragma unroll
      for(int g=0; g<4; ++g){
        acc[0][g]=mfma16(h0, whhf[g][kt], acc[0][g]);
        acc[1][g]=mfma16(h1, whhf[g][kt], acc[1][g]);
      }
      #pragma unroll
      for(int g=0; g<4; ++g){
        acc[0][g]=mfma16(xa[0][kt], wihf[g][kt], acc[0][g]);
        acc[1][g]=mfma16(xa[1][kt], wihf[g][kt], acc[1][g]);
      }
    }
    __syncthreads();   // all h reads done before overwriting hbuf
    #pragma unroll
    for(int m=0;m<2;++m){
      #pragma unroll
      for(int r=0;r<4;++r){
        float gi = acc[m][0][r] + bs[0];
        float gf = acc[m][1][r] + bs[1];
        float gg = acc[m][2][r] + bs[2];
        float go = acc[m][3][r] + bs[3];
        float i_ = sigm(gi), f_ = sigm(gf), o_ = sigm(go), g_ = tanh_(gg);
        float cc = f_*c[m][r] + i_*g_;
        c[m][r] = cc;
        float hh = o_*tanh_(cc);
        hreg[m][r] = hh;
        int row = m*16 + lhi*4 + r;
        int wb = (row*256 + ucol*2) ^ ((row&7)<<4);
        *(short*)((char*)hbuf + wb) = f2bf(hh);
      }
    }
    __syncthreads();   // new h visible
  }
  #pragma unroll
  for(int m=0;m<2;++m) for(int r=0;r<4;++r){
    int row = nbase + m*16 + lhi*4 + r;
    feat[(size_t)row*128 + ucol] = hreg[m][r];
  }
}

// ---------- 2) Y1t[j][n] = (feat @ gc1_W)[n][j], bf16 ----------
// grid 256 x 256. Block = 32 rows; thread = one output column j.
__global__ __launch_bounds__(256) void gc1_kernel(
  const float* __restrict__ feat, const float* __restrict__ W1,
  short* __restrict__ Y1t)
{
  __shared__ float fs[128][36];   // feat tile transposed [k][n], padded
  int tid = threadIdx.x; int nb = blockIdx.x*32;
  #pragma unroll
  for(int i=0;i<4;++i){
    int idx = i*256 + tid;                       // float4 index over [32][32]
    float4 v = ((const float4*)(feat + (size_t)nb*128))[idx];
    int n = idx>>5, k0 = (idx&31)*4;
    fs[k0][n]=v.x; fs[k0+1][n]=v.y; fs[k0+2][n]=v.z; fs[k0+3][n]=v.w;
  }
  __syncthreads();
  float acc[32];
  #pragma unroll
  for(int n=0;n<32;++n) acc[n]=0.f;
  int j = tid;
  for(int k=0;k<128;++k){
    float w = W1[k*256 + j];
    #pragma unroll
    for(int n4=0;n4<8;++n4){
      float4 f = *(const float4*)&fs[k][n4*4];
      acc[n4*4+0]+=f.x*w; acc[n4*4+1]+=f.y*w; acc[n4*4+2]+=f.z*w; acc[n4*4+3]+=f.w*w;
    }
  }
  unsigned* dst = (unsigned*)(Y1t + (size_t)j*8192 + nb);
  #pragma unroll
  for(int n=0;n<16;++n){
    unsigned lo = (unsigned short)f2bf(acc[2*n]);
    unsigned hi = (unsigned short)f2bf(acc[2*n+1]);
    dst[n] = lo | (hi<<16);
  }
}

// ---------- 3) part[ks] += adj @ Y1 (bf16 MFMA, split-K=4) ----------
// grid 512 (128 row-tiles x 4 ksplits) x 256. BM=64, BN=256, BK=32.
__global__ __launch_bounds__(256) void gemm1_kernel(
  const float* __restrict__ adj, const short* __restrict__ Y1t,
  float* __restrict__ part)
{
  __shared__ short As[64*40];       // bf16 A tile, row stride 40 (80B) vs conflicts
  int tid=threadIdx.x, lane=tid&63, wid=tid>>6;
  int wr=wid>>1, wc=wid&1, l15=lane&15, lhi=lane>>4;
  int rb=(blockIdx.x>>2)*64;
  int ks=blockIdx.x&3;
  size_t kb0=(size_t)ks*2048;
  f32x4 acc[2][8];
  #pragma unroll
  for(int m=0;m<2;++m) for(int n=0;n<8;++n) acc[m][n]=(f32x4){0.f,0.f,0.f,0.f};
  int arow=tid>>2, aq=tid&3;
  const float* asrc = adj + (size_t)(rb+arow)*8192 + kb0 + aq*8;
  short* adst = As + arow*40 + aq*8;
  for(int kt=0; kt<64; ++kt){
    float4 f0=((const float4*)asrc)[0], f1=((const float4*)asrc)[1];
    __syncthreads();
    *(bf16x8*)adst = pack8(f0,f1);
    __syncthreads();
    bf16x8 af[2];
    #pragma unroll
    for(int m=0;m<2;++m)
      af[m] = *(const bf16x8*)(As + (wr*32+m*16+l15)*40 + lhi*8);
    const short* yb = Y1t + kb0 + kt*32 + lhi*8;
    #pragma unroll
    for(int n=0;n<8;++n){
      bf16x8 bf_ = *(const bf16x8*)(yb + (size_t)(wc*128+n*16+l15)*8192);
      #pragma unroll
      for(int m=0;m<2;++m) acc[m][n]=mfma16(af[m], bf_, acc[m][n]);
    }
    asrc += 32;
  }
  float* pb = part + ((size_t)ks*8192 + rb)*256;
  #pragma unroll
  for(int m=0;m<2;++m) for(int n=0;n<8;++n){
    int row0=wr*32+m*16+lhi*4, col=wc*128+n*16+l15;
    #pragma unroll
    for(int r=0;r<4;++r) pb[(size_t)(row0+r)*256+col]=acc[m][n][r];
  }
}

// ---------- 4) h1 = relu(sum_k part + b1); Y2 = h1 @ gc2_W ----------
// grid 1024 x 256; 8 rows per block.
__global__ __launch_bounds__(256) void reduce_kernel(
  const float* __restrict__ part, const float* __restrict__ b1,
  const float* __restrict__ W2, float* __restrict__ Y2)
{
  __shared__ float h1s[8][256];
  __shared__ float w2s[256*16];
  int tid=threadIdx.x, rb=blockIdx.x*8;
  for(int i=tid;i<1024;i+=256) ((float4*)w2s)[i]=((const float4*)W2)[i];
  int r=tid>>5, cb=(tid&31)*8;
  const float* p0 = part + (size_t)(rb+r)*256 + cb;
  float a[8];
  #pragma unroll
  for(int q=0;q<8;++q) a[q]=0.f;
  #pragma unroll
  for(int ks=0;ks<4;++ks){
    const float* p = p0 + (size_t)ks*2097152;
    float4 u=((const float4*)p)[0], v=((const float4*)p)[1];
    a[0]+=u.x; a[1]+=u.y; a[2]+=u.z; a[3]+=u.w;
    a[4]+=v.x; a[5]+=v.y; a[6]+=v.z; a[7]+=v.w;
  }
  #pragma unroll
  for(int q=0;q<8;++q){
    float v = a[q] + b1[cb+q];
    h1s[r][cb+q] = v>0.f ? v : 0.f;
  }
  __syncthreads();
  if(tid<128){
    int rr=tid>>4, j=tid&15;
    float s=0.f;
    for(int k4=0;k4<64;++k4){
      float4 h = *(const float4*)&h1s[rr][k4*4];
      s += h.x*w2s[(k4*4+0)*16+j] + h.y*w2s[(k4*4+1)*16+j]
         + h.z*w2s[(k4*4+2)*16+j] + h.w*w2s[(k4*4+3)*16+j];
    }
    Y2[(size_t)(rb+rr)*16+j]=s;
  }
}

// ---------- 5) out = log_softmax(adj @ Y2 + b2) ----------
// grid 512 x 256; 16 rows per block; 16 k-stripe threads per row (f32 VALU).
__global__ __launch_bounds__(256) void gemm2_kernel(
  const float* __restrict__ adj, const float* __restrict__ Y2,
  const float* __restrict__ b2, float* __restrict__ out)
{
  __shared__ float y2t[16][516];       // transposed chunk, stride 516 (=4 mod 32)
  __shared__ float red[16][16][16];    // [row][j][stripe]
  int tid=threadIdx.x;
  int rb=blockIdx.x*16;
  int r=tid>>4, st=tid&15;
  float acc[16];
  #pragma unroll
  for(int j=0;j<16;++j) acc[j]=0.f;
  int sj = tid&15, skb = tid>>4;
  for(int kc=0;kc<16;++kc){
    __syncthreads();                    // protect previous chunk's reads
    const float* ysrc = Y2 + (size_t)(kc*512)*16;
    for(int kk=0;kk<32;++kk){
      int k = skb*32 + kk;
      y2t[sj][k] = ysrc[k*16 + sj];
    }
    __syncthreads();
    const float* arow = adj + (size_t)(rb+r)*8192 + kc*512 + st*4;
    #pragma unroll
    for(int i=0;i<8;++i){
      float4 av = *(const float4*)(arow + i*64);
      int k = st*4 + i*64;
      #pragma unroll
      for(int j=0;j<16;++j){
        float4 y = *(const float4*)&y2t[j][k];
        acc[j] += av.x*y.x + av.y*y.y + av.z*y.z + av.w*y.w;
      }
    }
  }
  #pragma unroll
  for(int j=0;j<16;++j) red[r][j][st]=acc[j];
  __syncthreads();
  int r2=tid>>4, j=tid&15;
  float s=0.f;
  #pragma unroll
  for(int q=0;q<16;q+=4){
    float4 v = *(const float4*)&red[r2][j][q];
    s += v.x+v.y+v.z+v.w;
  }
  float logit = s + b2[j];
  float m = logit;
  for(int msk=8;msk;msk>>=1) m = fmaxf(m, __shfl_xor(m, msk, 16));
  float e = __expf(logit - m);
  float den = e;
  for(int msk=8;msk;msk>>=1) den += __shfl_xor(den, msk, 16);
  out[(size_t)(rb+r2)*16 + j] = logit - m - __logf(den);
}

// ---------- launch ----------
extern "C" void kernel_launch(void* const* d_in, const int* in_sizes, int n_in,
                              void* d_out, int out_size, void* d_ws, size_t ws_size,
                              hipStream_t stream) {
  const int*   tokens = (const int*)d_in[0];
  const float* adj    = (const float*)d_in[1];
  const float* embed  = (const float*)d_in[2];
  const float* Wih    = (const float*)d_in[3];
  const float* Whh    = (const float*)d_in[4];
  const float* bih    = (const float*)d_in[5];
  const float* bhh    = (const float*)d_in[6];
  const float* W1     = (const float*)d_in[7];
  const float* b1     = (const float*)d_in[8];
  const float* W2     = (const float*)d_in[9];
  const float* b2     = (const float*)d_in[10];
  float* out = (float*)d_out;

  char* ws = (char*)d_ws;
  float* feat = (float*)ws;                       // 4 MB
  short* Y1t  = (short*)(ws + (4u<<20));          // 4 MB  (bf16 [256][8192])
  float* part = (float*)(ws + (8u<<20));          // 32 MB (4 x [8192][256] f32)
  float* Y2   = (float*)(ws + (40u<<20));         // 0.5 MB

  lstm_kernel  <<<dim3(256),  dim3(512), 0, stream>>>(tokens, embed, Wih, Whh, bih, bhh, feat);
  gc1_kernel   <<<dim3(256),  dim3(256), 0, stream>>>(feat, W1, Y1t);
  gemm1_kernel <<<dim3(512),  dim3(256), 0, stream>>>(adj, Y1t, part);
  reduce_kernel<<<dim3(1024), dim3(256), 0, stream>>>(part, b1, W2, Y2);
  gemm2_kernel <<<dim3(512),  dim3(256), 0, stream>>>(adj, Y2, b2, out);
}

// Round 3
// 759.552 us; speedup vs baseline: 1.1058x; 1.1058x over previous
//
#include <hip/hip_runtime.h>

// ---------- common helpers ----------
typedef __attribute__((ext_vector_type(8))) short bf16x8;
typedef __attribute__((ext_vector_type(4))) float f32x4;

__device__ __forceinline__ short f2bf(float f){
  union { float f; unsigned u; } v; v.f = f;
  unsigned r = v.u + 0x7fffu + ((v.u >> 16) & 1u);   // RNE
  return (short)(r >> 16);
}
__device__ __forceinline__ bf16x8 pack8(float4 a, float4 b){
  bf16x8 v;
  v[0]=f2bf(a.x); v[1]=f2bf(a.y); v[2]=f2bf(a.z); v[3]=f2bf(a.w);
  v[4]=f2bf(b.x); v[5]=f2bf(b.y); v[6]=f2bf(b.z); v[7]=f2bf(b.w);
  return v;
}
__device__ __forceinline__ f32x4 mfma16(bf16x8 a, bf16x8 b, f32x4 c){
  return __builtin_amdgcn_mfma_f32_16x16x32_bf16(a, b, c, 0, 0, 0);
}
__device__ __forceinline__ float sigm(float x){
  return __builtin_amdgcn_rcpf(1.f + __expf(-x));
}
__device__ __forceinline__ float tanh_(float x){
  return 1.f - 2.f*__builtin_amdgcn_rcpf(1.f + __expf(2.f*x));
}

// ---------- 1) embedding + LSTM (final h) ----------
// 256 blocks x 512 thr, 32 rows/block, wave w owns units [16w,16w+16).
// x-tile (embed gather) staged ONCE per block per step into LDS (dbuf),
// pipelined one step ahead; h dbuf'd -> 1 barrier/step.
// __launch_bounds__(512,2): 256-VGPR budget so the 128 weight-frag VGPRs
// do NOT spill (r1 had 128-cap -> scratch thrash, 225us).
__global__ __launch_bounds__(512,2) void lstm_kernel(
    const int* __restrict__ tokens, const float* __restrict__ embed,
    const float* __restrict__ Wih, const float* __restrict__ Whh,
    const float* __restrict__ bih, const float* __restrict__ bhh,
    float* __restrict__ feat)
{
  __shared__ short hbuf[2*32*128];   // 16 KB, XOR-swizzled rows of 256B
  __shared__ short xbuf[2*32*128];   // 16 KB, same layout
  __shared__ int   tokbuf[32*32];    // 4 KB
  const int tid  = threadIdx.x;
  const int wave = tid >> 6, lane = tid & 63;
  const int l15  = lane & 15, lhi = lane >> 4;
  const int nbase = blockIdx.x * 32;
  const int ucol  = wave*16 + l15;

  // weight B-frags in registers: B[k][col] = W[gate*128+ucol][k]
  bf16x8 wihf[4][4], whhf[4][4];
  #pragma unroll
  for(int g=0; g<4; ++g){
    const float* wi = Wih + (size_t)(g*128 + ucol)*128;
    const float* wh = Whh + (size_t)(g*128 + ucol)*128;
    #pragma unroll
    for(int kt=0; kt<4; ++kt){
      int e0 = kt*32 + lhi*8;
      float4 a0 = *(const float4*)(wi+e0), a1 = *(const float4*)(wi+e0+4);
      float4 b0 = *(const float4*)(wh+e0), b1 = *(const float4*)(wh+e0+4);
      wihf[g][kt] = pack8(a0,a1);
      whhf[g][kt] = pack8(b0,b1);
    }
  }
  float bs[4];
  #pragma unroll
  for(int g=0; g<4; ++g) bs[g] = bih[g*128+ucol] + bhh[g*128+ucol];

  // tokens for this block: contiguous 1024 ints
  for(int i=tid; i<1024; i+=512) tokbuf[i] = tokens[(size_t)nbase*32 + i];

  float c[2][4], hreg[2][4];
  #pragma unroll
  for(int m=0;m<2;++m) for(int r=0;r<4;++r){ c[m][r]=0.f; hreg[m][r]=0.f; }

  // zero hbuf[0]
  *(bf16x8*)((char*)hbuf + tid*16) = (bf16x8){0,0,0,0,0,0,0,0};
  __syncthreads();   // tokbuf ready

  // staging roles: thread -> (srow, sseg) of the 32x128 x-tile
  const int srow = tid >> 4, sseg = tid & 15;
  // prologue: stage x(0) into xbuf[0]
  {
    int tok = tokbuf[srow*32 + 0];
    const float* e = embed + (size_t)tok*128 + sseg*8;
    float4 a = *(const float4*)e, b = *(const float4*)(e+4);
    int byte = (srow*256 + sseg*16) ^ ((srow&7)<<4);
    *(bf16x8*)((char*)xbuf + byte) = pack8(a,b);
  }
  __syncthreads();

  float4 sa, sb;
  #pragma unroll 1
  for(int l=0; l<32; ++l){
    // issue next step's gather early (latency hidden under MFMA)
    if(l < 31){
      int tok = tokbuf[srow*32 + l + 1];
      const float* e = embed + (size_t)tok*128 + sseg*8;
      sa = *(const float4*)e; sb = *(const float4*)(e+4);
    }
    const char* hb = (const char*)hbuf + (l&1)*8192;
    const char* xb = (const char*)xbuf + (l&1)*8192;
    f32x4 acc[2][4];
    #pragma unroll
    for(int m=0;m<2;++m) for(int g=0;g<4;++g) acc[m][g]=(f32x4){0.f,0.f,0.f,0.f};
    #pragma unroll
    for(int kt=0; kt<4; ++kt){
      int cbyte = kt*64 + lhi*16;
      int swz = (l15&7)<<4;
      int a0 = (l15*256 + cbyte) ^ swz;
      int a1 = ((16+l15)*256 + cbyte) ^ swz;
      bf16x8 h0 = *(const bf16x8*)(hb + a0);
      bf16x8 h1 = *(const bf16x8*)(hb + a1);
      bf16x8 x0 = *(const bf16x8*)(xb + a0);
      bf16x8 x1 = *(const bf16x8*)(xb + a1);
      #pragma unroll
      for(int g=0; g<4; ++g){
        acc[0][g]=mfma16(h0, whhf[g][kt], acc[0][g]);
        acc[1][g]=mfma16(h1, whhf[g][kt], acc[1][g]);
        acc[0][g]=mfma16(x0, wihf[g][kt], acc[0][g]);
        acc[1][g]=mfma16(x1, wihf[g][kt], acc[1][g]);
      }
    }
    // elementwise + h write into the OTHER h buffer
    char* hn = (char*)hbuf + ((l+1)&1)*8192;
    #pragma unroll
    for(int m=0;m<2;++m){
      #pragma unroll
      for(int r=0;r<4;++r){
        float gi = acc[m][0][r] + bs[0];
        float gf = acc[m][1][r] + bs[1];
        float gg = acc[m][2][r] + bs[2];
        float go = acc[m][3][r] + bs[3];
        float i_ = sigm(gi), f_ = sigm(gf), o_ = sigm(go), g_ = tanh_(gg);
        float cc = f_*c[m][r] + i_*g_;
        c[m][r] = cc;
        float hh = o_*tanh_(cc);
        hreg[m][r] = hh;
        int row = m*16 + lhi*4 + r;
        int wb = (row*256 + ucol*2) ^ ((row&7)<<4);
        *(short*)(hn + wb) = f2bf(hh);
      }
    }
    // finish staging x(l+1)
    if(l < 31){
      int byte = ((l+1)&1)*8192 + ((srow*256 + sseg*16) ^ ((srow&7)<<4));
      *(bf16x8*)((char*)xbuf + byte) = pack8(sa,sb);
    }
    __syncthreads();
  }
  #pragma unroll
  for(int m=0;m<2;++m) for(int r=0;r<4;++r){
    int row = nbase + m*16 + lhi*4 + r;
    feat[(size_t)row*128 + ucol] = hreg[m][r];
  }
}

// ---------- 2) Y1t[j][n] = (feat @ gc1_W)[n][j], bf16 ----------
__global__ __launch_bounds__(256) void gc1_kernel(
  const float* __restrict__ feat, const float* __restrict__ W1,
  short* __restrict__ Y1t)
{
  __shared__ float fs[128][36];   // feat tile transposed [k][n], padded
  int tid = threadIdx.x; int nb = blockIdx.x*32;
  #pragma unroll
  for(int i=0;i<4;++i){
    int idx = i*256 + tid;
    float4 v = ((const float4*)(feat + (size_t)nb*128))[idx];
    int n = idx>>5, k0 = (idx&31)*4;
    fs[k0][n]=v.x; fs[k0+1][n]=v.y; fs[k0+2][n]=v.z; fs[k0+3][n]=v.w;
  }
  __syncthreads();
  float acc[32];
  #pragma unroll
  for(int n=0;n<32;++n) acc[n]=0.f;
  int j = tid;
  for(int k=0;k<128;++k){
    float w = W1[k*256 + j];
    #pragma unroll
    for(int n4=0;n4<8;++n4){
      float4 f = *(const float4*)&fs[k][n4*4];
      acc[n4*4+0]+=f.x*w; acc[n4*4+1]+=f.y*w; acc[n4*4+2]+=f.z*w; acc[n4*4+3]+=f.w*w;
    }
  }
  unsigned* dst = (unsigned*)(Y1t + (size_t)j*8192 + nb);
  #pragma unroll
  for(int n=0;n<16;++n){
    unsigned lo = (unsigned short)f2bf(acc[2*n]);
    unsigned hi = (unsigned short)f2bf(acc[2*n+1]);
    dst[n] = lo | (hi<<16);
  }
}

// ---------- 3) part[ks] = adj @ Y1 slice (bf16 MFMA, split-K=4) ----------
// grid 256 (64 row-tiles x 4 ksplits) x 512 thr. BM=128, BN=256, BK=128.
// Double-buffered XOR-swizzled LDS A-tile, reg-staged, 1 barrier/K-step,
// next-step loads issued before MFMA (overlap).
__global__ __launch_bounds__(512,2) void gemm1_kernel(
  const float* __restrict__ adj, const short* __restrict__ Y1t,
  float* __restrict__ part)
{
  __shared__ short As[2*128*128];     // 64 KB
  int tid=threadIdx.x, lane=tid&63, wid=tid>>6;
  int wr=wid>>2, wc=wid&3, l15=lane&15, lhi=lane>>4;
  int rb=(blockIdx.x>>2)*128;
  int ks=blockIdx.x&3;
  size_t kb0=(size_t)ks*2048;
  f32x4 acc[4][4];
  #pragma unroll
  for(int m=0;m<4;++m) for(int n=0;n<4;++n) acc[m][n]=(f32x4){0.f,0.f,0.f,0.f};

  const int srow = tid>>2, sseg = tid&3;           // stage 32 floats/thread
  const float* asrc = adj + (size_t)(rb+srow)*8192 + kb0 + sseg*32;
  float4 r[8];
  {
    const float4* p = (const float4*)asrc;
    #pragma unroll
    for(int i=0;i<8;++i) r[i]=p[i];
  }
  #pragma unroll 1
  for(int t=0; t<16; ++t){
    // write staged regs -> As[t&1]
    char* dst = (char*)As + (t&1)*32768;
    #pragma unroll
    for(int q=0;q<4;++q){
      int byte = (srow*256 + (sseg*32+q*8)*2) ^ ((srow&7)<<4);
      *(bf16x8*)(dst + byte) = pack8(r[2*q], r[2*q+1]);
    }
    __syncthreads();
    // issue next A loads (overlap with MFMA below)
    if(t<15){
      const float4* p = (const float4*)(asrc + (t+1)*128);
      #pragma unroll
      for(int i=0;i<8;++i) r[i]=p[i];
    }
    // compute on As[t&1]
    const char* cur = (const char*)As + (t&1)*32768;
    #pragma unroll
    for(int kk=0;kk<4;++kk){
      bf16x8 af[4];
      #pragma unroll
      for(int m=0;m<4;++m){
        int row = wr*64 + m*16 + l15;
        int byte = (row*256 + (kk*32+lhi*8)*2) ^ ((row&7)<<4);
        af[m] = *(const bf16x8*)(cur + byte);
      }
      const short* yb = Y1t + kb0 + t*128 + kk*32 + lhi*8;
      #pragma unroll
      for(int n=0;n<4;++n){
        bf16x8 bfr = *(const bf16x8*)(yb + (size_t)(wc*64 + n*16 + l15)*8192);
        #pragma unroll
        for(int m=0;m<4;++m) acc[m][n]=mfma16(af[m], bfr, acc[m][n]);
      }
    }
    __syncthreads();   // all reads of As[t&1] done before it is overwritten
  }
  float* pb = part + ((size_t)ks*8192 + rb)*256;
  #pragma unroll
  for(int m=0;m<4;++m) for(int n=0;n<4;++n){
    int row0=wr*64+m*16+lhi*4, col=wc*64+n*16+l15;
    #pragma unroll
    for(int q=0;q<4;++q) pb[(size_t)(row0+q)*256+col]=acc[m][n][q];
  }
}

// ---------- 4) h1 = relu(sum_k part + b1); Y2 = h1 @ gc2_W ----------
__global__ __launch_bounds__(256) void reduce_kernel(
  const float* __restrict__ part, const float* __restrict__ b1,
  const float* __restrict__ W2, float* __restrict__ Y2)
{
  __shared__ float h1s[8][256];
  __shared__ float w2s[256*16];
  int tid=threadIdx.x, rb=blockIdx.x*8;
  for(int i=tid;i<1024;i+=256) ((float4*)w2s)[i]=((const float4*)W2)[i];
  int r=tid>>5, cb=(tid&31)*8;
  const float* p0 = part + (size_t)(rb+r)*256 + cb;
  float a[8];
  #pragma unroll
  for(int q=0;q<8;++q) a[q]=0.f;
  #pragma unroll
  for(int ks=0;ks<4;++ks){
    const float* p = p0 + (size_t)ks*2097152;
    float4 u=((const float4*)p)[0], v=((const float4*)p)[1];
    a[0]+=u.x; a[1]+=u.y; a[2]+=u.z; a[3]+=u.w;
    a[4]+=v.x; a[5]+=v.y; a[6]+=v.z; a[7]+=v.w;
  }
  #pragma unroll
  for(int q=0;q<8;++q){
    float v = a[q] + b1[cb+q];
    h1s[r][cb+q] = v>0.f ? v : 0.f;
  }
  __syncthreads();
  if(tid<128){
    int rr=tid>>4, j=tid&15;
    float s=0.f;
    for(int k4=0;k4<64;++k4){
      float4 h = *(const float4*)&h1s[rr][k4*4];
      s += h.x*w2s[(k4*4+0)*16+j] + h.y*w2s[(k4*4+1)*16+j]
         + h.z*w2s[(k4*4+2)*16+j] + h.w*w2s[(k4*4+3)*16+j];
    }
    Y2[(size_t)(rb+rr)*16+j]=s;
  }
}

// ---------- 5) out = log_softmax(adj @ Y2 + b2) ----------
// 512 blocks x 256 thr. Wave owns 4 rows; lane owns 4-consecutive-k stripes.
// No LDS staging, no barriers in the main loop; 64-lane butterfly at end.
__global__ __launch_bounds__(256) void gemm2_kernel(
  const float* __restrict__ adj, const float* __restrict__ Y2,
  const float* __restrict__ b2, float* __restrict__ out)
{
  __shared__ float red[16][16];
  int tid=threadIdx.x, lane=tid&63, w=tid>>6;
  int rb=blockIdx.x*16;
  int rowb=rb + w*4;
  float acc[4][16];
  #pragma unroll
  for(int rr=0;rr<4;++rr) for(int j=0;j<16;++j) acc[rr][j]=0.f;
  const float* a0 = adj + (size_t)rowb*8192;
  #pragma unroll 1
  for(int it=0; it<32; ++it){
    int kb = it*256 + lane*4;
    float4 av[4];
    #pragma unroll
    for(int rr=0;rr<4;++rr) av[rr] = *(const float4*)(a0 + (size_t)rr*8192 + kb);
    #pragma unroll
    for(int kk=0;kk<4;++kk){
      const float* yr = Y2 + (size_t)(kb+kk)*16;
      float4 y0=*(const float4*)yr,      y1=*(const float4*)(yr+4);
      float4 y2v=*(const float4*)(yr+8), y3=*(const float4*)(yr+12);
      #pragma unroll
      for(int rr=0;rr<4;++rr){
        float a = (kk==0)?av[rr].x:(kk==1)?av[rr].y:(kk==2)?av[rr].z:av[rr].w;
        acc[rr][0] +=a*y0.x;  acc[rr][1] +=a*y0.y;  acc[rr][2] +=a*y0.z;  acc[rr][3] +=a*y0.w;
        acc[rr][4] +=a*y1.x;  acc[rr][5] +=a*y1.y;  acc[rr][6] +=a*y1.z;  acc[rr][7] +=a*y1.w;
        acc[rr][8] +=a*y2v.x; acc[rr][9] +=a*y2v.y; acc[rr][10]+=a*y2v.z; acc[rr][11]+=a*y2v.w;
        acc[rr][12]+=a*y3.x;  acc[rr][13]+=a*y3.y;  acc[rr][14]+=a*y3.z;  acc[rr][15]+=a*y3.w;
      }
    }
  }
  // butterfly reduce across 64 lanes (k-stripes)
  #pragma unroll
  for(int mask=32; mask; mask>>=1){
    #pragma unroll
    for(int rr=0;rr<4;++rr)
      #pragma unroll
      for(int j=0;j<16;++j)
        acc[rr][j] += __shfl_xor(acc[rr][j], mask);
  }
  if(lane==0){
    #pragma unroll
    for(int rr=0;rr<4;++rr)
      #pragma unroll
      for(int j=0;j<16;++j) red[w*4+rr][j]=acc[rr][j];
  }
  __syncthreads();
  int r2=tid>>4, j=tid&15;
  float logit = red[r2][j] + b2[j];
  float m = logit;
  for(int msk=8;msk;msk>>=1) m = fmaxf(m, __shfl_xor(m, msk, 16));
  float e = __expf(logit - m);
  float den = e;
  for(int msk=8;msk;msk>>=1) den += __shfl_xor(den, msk, 16);
  out[(size_t)(rb+r2)*16 + j] = logit - m - __logf(den);
}

// ---------- launch ----------
extern "C" void kernel_launch(void* const* d_in, const int* in_sizes, int n_in,
                              void* d_out, int out_size, void* d_ws, size_t ws_size,
                              hipStream_t stream) {
  const int*   tokens = (const int*)d_in[0];
  const float* adj    = (const float*)d_in[1];
  const float* embed  = (const float*)d_in[2];
  const float* Wih    = (const float*)d_in[3];
  const float* Whh    = (const float*)d_in[4];
  const float* bih    = (const float*)d_in[5];
  const float* bhh    = (const float*)d_in[6];
  const float* W1     = (const float*)d_in[7];
  const float* b1     = (const float*)d_in[8];
  const float* W2     = (const float*)d_in[9];
  const float* b2     = (const float*)d_in[10];
  float* out = (float*)d_out;

  char* ws = (char*)d_ws;
  float* feat = (float*)ws;                       // 4 MB
  short* Y1t  = (short*)(ws + (4u<<20));          // 4 MB  (bf16 [256][8192])
  float* part = (float*)(ws + (8u<<20));          // 32 MB (4 x [8192][256] f32)
  float* Y2   = (float*)(ws + (40u<<20));         // 0.5 MB

  lstm_kernel  <<<dim3(256),  dim3(512), 0, stream>>>(tokens, embed, Wih, Whh, bih, bhh, feat);
  gc1_kernel   <<<dim3(256),  dim3(256), 0, stream>>>(feat, W1, Y1t);
  gemm1_kernel <<<dim3(256),  dim3(512), 0, stream>>>(adj, Y1t, part);
  reduce_kernel<<<dim3(1024), dim3(256), 0, stream>>>(part, b1, W2, Y2);
  gemm2_kernel <<<dim3(512),  dim3(256), 0, stream>>>(adj, Y2, b2, out);
}

// Round 6
// 695.120 us; speedup vs baseline: 1.2083x; 1.0927x over previous
//
#include <hip/hip_runtime.h>

// ---------- common helpers ----------
typedef __attribute__((ext_vector_type(8))) short bf16x8;
typedef __attribute__((ext_vector_type(4))) float f32x4;

__device__ __forceinline__ short f2bf(float f){
  union { float f; unsigned u; } v; v.f = f;
  unsigned r = v.u + 0x7fffu + ((v.u >> 16) & 1u);   // RNE
  return (short)(r >> 16);
}
__device__ __forceinline__ bf16x8 pack8(float4 a, float4 b){
  bf16x8 v;
  v[0]=f2bf(a.x); v[1]=f2bf(a.y); v[2]=f2bf(a.z); v[3]=f2bf(a.w);
  v[4]=f2bf(b.x); v[5]=f2bf(b.y); v[6]=f2bf(b.z); v[7]=f2bf(b.w);
  return v;
}
__device__ __forceinline__ f32x4 mfma16(bf16x8 a, bf16x8 b, f32x4 c){
  return __builtin_amdgcn_mfma_f32_16x16x32_bf16(a, b, c, 0, 0, 0);
}
__device__ __forceinline__ float sigm(float x){
  return __builtin_amdgcn_rcpf(1.f + __expf(-x));
}
__device__ __forceinline__ float tanh_(float x){
  return 1.f - 2.f*__builtin_amdgcn_rcpf(1.f + __expf(2.f*x));
}

// ---------- 1) embedding + LSTM (final h) ---------- (unchanged from r3)
__global__ __launch_bounds__(512,2) void lstm_kernel(
    const int* __restrict__ tokens, const float* __restrict__ embed,
    const float* __restrict__ Wih, const float* __restrict__ Whh,
    const float* __restrict__ bih, const float* __restrict__ bhh,
    float* __restrict__ feat)
{
  __shared__ short hbuf[2*32*128];   // 16 KB, XOR-swizzled rows of 256B
  __shared__ short xbuf[2*32*128];   // 16 KB, same layout
  __shared__ int   tokbuf[32*32];    // 4 KB
  const int tid  = threadIdx.x;
  const int wave = tid >> 6, lane = tid & 63;
  const int l15  = lane & 15, lhi = lane >> 4;
  const int nbase = blockIdx.x * 32;
  const int ucol  = wave*16 + l15;

  bf16x8 wihf[4][4], whhf[4][4];
  #pragma unroll
  for(int g=0; g<4; ++g){
    const float* wi = Wih + (size_t)(g*128 + ucol)*128;
    const float* wh = Whh + (size_t)(g*128 + ucol)*128;
    #pragma unroll
    for(int kt=0; kt<4; ++kt){
      int e0 = kt*32 + lhi*8;
      float4 a0 = *(const float4*)(wi+e0), a1 = *(const float4*)(wi+e0+4);
      float4 b0 = *(const float4*)(wh+e0), b1 = *(const float4*)(wh+e0+4);
      wihf[g][kt] = pack8(a0,a1);
      whhf[g][kt] = pack8(b0,b1);
    }
  }
  float bs[4];
  #pragma unroll
  for(int g=0; g<4; ++g) bs[g] = bih[g*128+ucol] + bhh[g*128+ucol];

  for(int i=tid; i<1024; i+=512) tokbuf[i] = tokens[(size_t)nbase*32 + i];

  float c[2][4], hreg[2][4];
  #pragma unroll
  for(int m=0;m<2;++m) for(int r=0;r<4;++r){ c[m][r]=0.f; hreg[m][r]=0.f; }

  *(bf16x8*)((char*)hbuf + tid*16) = (bf16x8){0,0,0,0,0,0,0,0};
  __syncthreads();

  const int srow = tid >> 4, sseg = tid & 15;
  {
    int tok = tokbuf[srow*32 + 0];
    const float* e = embed + (size_t)tok*128 + sseg*8;
    float4 a = *(const float4*)e, b = *(const float4*)(e+4);
    int byte = (srow*256 + sseg*16) ^ ((srow&7)<<4);
    *(bf16x8*)((char*)xbuf + byte) = pack8(a,b);
  }
  __syncthreads();

  float4 sa, sb;
  #pragma unroll 1
  for(int l=0; l<32; ++l){
    if(l < 31){
      int tok = tokbuf[srow*32 + l + 1];
      const float* e = embed + (size_t)tok*128 + sseg*8;
      sa = *(const float4*)e; sb = *(const float4*)(e+4);
    }
    const char* hb = (const char*)hbuf + (l&1)*8192;
    const char* xb = (const char*)xbuf + (l&1)*8192;
    f32x4 acc[2][4];
    #pragma unroll
    for(int m=0;m<2;++m) for(int g=0;g<4;++g) acc[m][g]=(f32x4){0.f,0.f,0.f,0.f};
    #pragma unroll
    for(int kt=0; kt<4; ++kt){
      int cbyte = kt*64 + lhi*16;
      int swz = (l15&7)<<4;
      int a0 = (l15*256 + cbyte) ^ swz;
      int a1 = ((16+l15)*256 + cbyte) ^ swz;
      bf16x8 h0 = *(const bf16x8*)(hb + a0);
      bf16x8 h1 = *(const bf16x8*)(hb + a1);
      bf16x8 x0 = *(const bf16x8*)(xb + a0);
      bf16x8 x1 = *(const bf16x8*)(xb + a1);
      #pragma unroll
      for(int g=0; g<4; ++g){
        acc[0][g]=mfma16(h0, whhf[g][kt], acc[0][g]);
        acc[1][g]=mfma16(h1, whhf[g][kt], acc[1][g]);
        acc[0][g]=mfma16(x0, wihf[g][kt], acc[0][g]);
        acc[1][g]=mfma16(x1, wihf[g][kt], acc[1][g]);
      }
    }
    char* hn = (char*)hbuf + ((l+1)&1)*8192;
    #pragma unroll
    for(int m=0;m<2;++m){
      #pragma unroll
      for(int r=0;r<4;++r){
        float gi = acc[m][0][r] + bs[0];
        float gf = acc[m][1][r] + bs[1];
        float gg = acc[m][2][r] + bs[2];
        float go = acc[m][3][r] + bs[3];
        float i_ = sigm(gi), f_ = sigm(gf), o_ = sigm(go), g_ = tanh_(gg);
        float cc = f_*c[m][r] + i_*g_;
        c[m][r] = cc;
        float hh = o_*tanh_(cc);
        hreg[m][r] = hh;
        int row = m*16 + lhi*4 + r;
        int wb = (row*256 + ucol*2) ^ ((row&7)<<4);
        *(short*)(hn + wb) = f2bf(hh);
      }
    }
    if(l < 31){
      int byte = ((l+1)&1)*8192 + ((srow*256 + sseg*16) ^ ((srow&7)<<4));
      *(bf16x8*)((char*)xbuf + byte) = pack8(sa,sb);
    }
    __syncthreads();
  }
  #pragma unroll
  for(int m=0;m<2;++m) for(int r=0;r<4;++r){
    int row = nbase + m*16 + lhi*4 + r;
    feat[(size_t)row*128 + ucol] = hreg[m][r];
  }
}

// ---------- 2) Y1t[j][n] = (feat @ gc1_W)[n][j], bf16 ----------
__global__ __launch_bounds__(256) void gc1_kernel(
  const float* __restrict__ feat, const float* __restrict__ W1,
  short* __restrict__ Y1t)
{
  __shared__ float fs[128][36];
  int tid = threadIdx.x; int nb = blockIdx.x*32;
  #pragma unroll
  for(int i=0;i<4;++i){
    int idx = i*256 + tid;
    float4 v = ((const float4*)(feat + (size_t)nb*128))[idx];
    int n = idx>>5, k0 = (idx&31)*4;
    fs[k0][n]=v.x; fs[k0+1][n]=v.y; fs[k0+2][n]=v.z; fs[k0+3][n]=v.w;
  }
  __syncthreads();
  float acc[32];
  #pragma unroll
  for(int n=0;n<32;++n) acc[n]=0.f;
  int j = tid;
  for(int k=0;k<128;++k){
    float w = W1[k*256 + j];
    #pragma unroll
    for(int n4=0;n4<8;++n4){
      float4 f = *(const float4*)&fs[k][n4*4];
      acc[n4*4+0]+=f.x*w; acc[n4*4+1]+=f.y*w; acc[n4*4+2]+=f.z*w; acc[n4*4+3]+=f.w*w;
    }
  }
  unsigned* dst = (unsigned*)(Y1t + (size_t)j*8192 + nb);
  #pragma unroll
  for(int n=0;n<16;++n){
    unsigned lo = (unsigned short)f2bf(acc[2*n]);
    unsigned hi = (unsigned short)f2bf(acc[2*n+1]);
    dst[n] = lo | (hi<<16);
  }
}

// ---------- 3) part[ks] = adj @ Y1 slice (bf16 MFMA, split-K=4) ----------
// r4: BM=64, 256 thr, LDS dbuf 32KB -> grid 512 = 2+ blocks/CU so barrier
// stalls of one block overlap the other's MFMA (r3: 1 block/CU, latency-bound
// at 14% HBM). Wave grid 2x2, wave tile 32x128, acc[2][8].
__global__ __launch_bounds__(256,2) void gemm1_kernel(
  const float* __restrict__ adj, const short* __restrict__ Y1t,
  float* __restrict__ part)
{
  __shared__ short As[2*64*128];     // 32 KB
  int tid=threadIdx.x, lane=tid&63, wid=tid>>6;
  int wr=wid>>1, wc=wid&1, l15=lane&15, lhi=lane>>4;
  int rb=(blockIdx.x>>2)*64;
  int ks=blockIdx.x&3;
  size_t kb0=(size_t)ks*2048;
  f32x4 acc[2][8];
  #pragma unroll
  for(int m=0;m<2;++m) for(int n=0;n<8;++n) acc[m][n]=(f32x4){0.f,0.f,0.f,0.f};

  const int srow = tid>>2, sseg = tid&3;           // stage 32 floats/thread
  const float* asrc = adj + (size_t)(rb+srow)*8192 + kb0 + sseg*32;
  float4 r[8];
  {
    const float4* p = (const float4*)asrc;
    #pragma unroll
    for(int i=0;i<8;++i) r[i]=p[i];
  }
  #pragma unroll 1
  for(int t=0; t<16; ++t){
    char* dst = (char*)As + (t&1)*16384;
    #pragma unroll
    for(int q=0;q<4;++q){
      int byte = (srow*256 + (sseg*32+q*8)*2) ^ ((srow&7)<<4);
      *(bf16x8*)(dst + byte) = pack8(r[2*q], r[2*q+1]);
    }
    __syncthreads();
    if(t<15){
      const float4* p = (const float4*)(asrc + (t+1)*128);
      #pragma unroll
      for(int i=0;i<8;++i) r[i]=p[i];
    }
    const char* cur = (const char*)As + (t&1)*16384;
    #pragma unroll
    for(int kk=0;kk<4;++kk){
      bf16x8 af[2];
      #pragma unroll
      for(int m=0;m<2;++m){
        int row = wr*32 + m*16 + l15;
        int byte = (row*256 + (kk*32+lhi*8)*2) ^ ((row&7)<<4);
        af[m] = *(const bf16x8*)(cur + byte);
      }
      const short* yb = Y1t + kb0 + t*128 + kk*32 + lhi*8;
      #pragma unroll
      for(int n=0;n<8;++n){
        bf16x8 bfr = *(const bf16x8*)(yb + (size_t)(wc*128 + n*16 + l15)*8192);
        #pragma unroll
        for(int m=0;m<2;++m) acc[m][n]=mfma16(af[m], bfr, acc[m][n]);
      }
    }
    __syncthreads();
  }
  float* pb = part + ((size_t)ks*8192 + rb)*256;
  #pragma unroll
  for(int m=0;m<2;++m) for(int n=0;n<8;++n){
    int row0=wr*32+m*16+lhi*4, col=wc*128+n*16+l15;
    #pragma unroll
    for(int q=0;q<4;++q) pb[(size_t)(row0+q)*256+col]=acc[m][n][q];
  }
}

// ---------- 4) h1 = relu(sum_k part + b1); Y2t = (h1 @ gc2_W)^T ----------
__global__ __launch_bounds__(256) void reduce_kernel(
  const float* __restrict__ part, const float* __restrict__ b1,
  const float* __restrict__ W2, float* __restrict__ Y2t)
{
  __shared__ float h1s[8][256];
  __shared__ float w2s[256*16];
  int tid=threadIdx.x, rb=blockIdx.x*8;
  for(int i=tid;i<1024;i+=256) ((float4*)w2s)[i]=((const float4*)W2)[i];
  int r=tid>>5, cb=(tid&31)*8;
  const float* p0 = part + (size_t)(rb+r)*256 + cb;
  float a[8];
  #pragma unroll
  for(int q=0;q<8;++q) a[q]=0.f;
  #pragma unroll
  for(int ks=0;ks<4;++ks){
    const float* p = p0 + (size_t)ks*2097152;
    float4 u=((const float4*)p)[0], v=((const float4*)p)[1];
    a[0]+=u.x; a[1]+=u.y; a[2]+=u.z; a[3]+=u.w;
    a[4]+=v.x; a[5]+=v.y; a[6]+=v.z; a[7]+=v.w;
  }
  #pragma unroll
  for(int q=0;q<8;++q){
    float v = a[q] + b1[cb+q];
    h1s[r][cb+q] = v>0.f ? v : 0.f;
  }
  __syncthreads();
  if(tid<128){
    int rr=tid>>4, j=tid&15;
    float s=0.f;
    for(int k4=0;k4<64;++k4){
      float4 h = *(const float4*)&h1s[rr][k4*4];
      s += h.x*w2s[(k4*4+0)*16+j] + h.y*w2s[(k4*4+1)*16+j]
         + h.z*w2s[(k4*4+2)*16+j] + h.w*w2s[(k4*4+3)*16+j];
    }
    Y2t[(size_t)j*8192 + rb + rr] = s;    // transposed for gemm2 coalescing
  }
}

// ---------- 5) out = log_softmax(adj @ Y2 + b2), Y2 given transposed ----------
// 512 blocks x 256 thr. Wave owns 4 rows; lane owns a 4-k stripe.
// Next-iter adj rows prefetched into regs so HBM latency hides under the
// 256-FMA compute block; Y2t rows are contiguous coalesced float4 reads.
__global__ __launch_bounds__(256,2) void gemm2_kernel(
  const float* __restrict__ adj, const float* __restrict__ Y2t,
  const float* __restrict__ b2, float* __restrict__ out)
{
  __shared__ float red[16][16];
  int tid=threadIdx.x, lane=tid&63, w=tid>>6;
  int rb=blockIdx.x*16;
  int rowb=rb + w*4;
  float acc[4][16];
  #pragma unroll
  for(int rr=0;rr<4;++rr) for(int j=0;j<16;++j) acc[rr][j]=0.f;
  const float* a0 = adj + (size_t)rowb*8192;
  float4 av[4];
  #pragma unroll
  for(int rr=0;rr<4;++rr) av[rr] = *(const float4*)(a0 + (size_t)rr*8192 + lane*4);
  #pragma unroll 1
  for(int it=0; it<32; ++it){
    float4 nv[4];
    if(it<31){
      int kbn = (it+1)*256 + lane*4;
      #pragma unroll
      for(int rr=0;rr<4;++rr) nv[rr] = *(const float4*)(a0 + (size_t)rr*8192 + kbn);
    }
    int kb = it*256 + lane*4;
    #pragma unroll
    for(int j=0;j<16;++j){
      float4 y = *(const float4*)(Y2t + (size_t)j*8192 + kb);
      #pragma unroll
      for(int rr=0;rr<4;++rr)
        acc[rr][j] += av[rr].x*y.x + av[rr].y*y.y + av[rr].z*y.z + av[rr].w*y.w;
    }
    #pragma unroll
    for(int rr=0;rr<4;++rr) av[rr]=nv[rr];
  }
  #pragma unroll
  for(int mask=32; mask; mask>>=1){
    #pragma unroll
    for(int rr=0;rr<4;++rr)
      #pragma unroll
      for(int j=0;j<16;++j)
        acc[rr][j] += __shfl_xor(acc[rr][j], mask);
  }
  if(lane==0){
    #pragma unroll
    for(int rr=0;rr<4;++rr)
      #pragma unroll
      for(int j=0;j<16;++j) red[w*4+rr][j]=acc[rr][j];
  }
  __syncthreads();
  int r2=tid>>4, j=tid&15;
  float logit = red[r2][j] + b2[j];
  float m = logit;
  for(int msk=8;msk;msk>>=1) m = fmaxf(m, __shfl_xor(m, msk, 16));
  float e = __expf(logit - m);
  float den = e;
  for(int msk=8;msk;msk>>=1) den += __shfl_xor(den, msk, 16);
  out[(size_t)(rb+r2)*16 + j] = logit - m - __logf(den);
}

// ---------- launch ----------
extern "C" void kernel_launch(void* const* d_in, const int* in_sizes, int n_in,
                              void* d_out, int out_size, void* d_ws, size_t ws_size,
                              hipStream_t stream) {
  const int*   tokens = (const int*)d_in[0];
  const float* adj    = (const float*)d_in[1];
  const float* embed  = (const float*)d_in[2];
  const float* Wih    = (const float*)d_in[3];
  const float* Whh    = (const float*)d_in[4];
  const float* bih    = (const float*)d_in[5];
  const float* bhh    = (const float*)d_in[6];
  const float* W1     = (const float*)d_in[7];
  const float* b1     = (const float*)d_in[8];
  const float* W2     = (const float*)d_in[9];
  const float* b2     = (const float*)d_in[10];
  float* out = (float*)d_out;

  char* ws = (char*)d_ws;
  float* feat = (float*)ws;                       // 4 MB
  short* Y1t  = (short*)(ws + (4u<<20));          // 4 MB  (bf16 [256][8192])
  float* part = (float*)(ws + (8u<<20));          // 32 MB (4 x [8192][256] f32)
  float* Y2t  = (float*)(ws + (40u<<20));         // 0.5 MB ([16][8192] f32)

  lstm_kernel  <<<dim3(256),  dim3(512), 0, stream>>>(tokens, embed, Wih, Whh, bih, bhh, feat);
  gc1_kernel   <<<dim3(256),  dim3(256), 0, stream>>>(feat, W1, Y1t);
  gemm1_kernel <<<dim3(512),  dim3(256), 0, stream>>>(adj, Y1t, part);
  reduce_kernel<<<dim3(1024), dim3(256), 0, stream>>>(part, b1, W2, Y2t);
  gemm2_kernel <<<dim3(512),  dim3(256), 0, stream>>>(adj, Y2t, b2, out);
}